// Round 2
// baseline (802.475 us; speedup 1.0000x reference)
//
#include <hip/hip_runtime.h>
#include <stdint.h>

// Problem: B=4, N=8192 -> 32768 tokens, E=1024, HQ=HKV=16, d=64.
#define NTOK 32768
#define NE   1024
#define NWEL 1048576   // 1024*1024 weight elements

typedef int v4i __attribute__((ext_vector_type(4)));
typedef __attribute__((ext_vector_type(8))) short bhalf8;  // 8 bf16 (4 VGPR)
typedef __attribute__((ext_vector_type(4))) float f32x4;

__device__ __forceinline__ float wave_sum(float v) {
#pragma unroll
  for (int o = 32; o; o >>= 1) v += __shfl_xor(v, o, 64);
  return v;
}
__device__ __forceinline__ float wave_max(float v) {
#pragma unroll
  for (int o = 32; o; o >>= 1) v = fmaxf(v, __shfl_xor(v, o, 64));
  return v;
}

__device__ __forceinline__ void gload_lds16(const void* gptr, void* ldsptr) {
  __builtin_amdgcn_global_load_lds(
      (const __attribute__((address_space(1))) void*)gptr,
      (__attribute__((address_space(3))) void*)ldsptr, 16, 0, 0);
}

// bf16 round-to-nearest-even helpers for hi/lo split (x ~= hi + lo, f32-grade)
__device__ __forceinline__ unsigned bf_rne(float f) {
  unsigned u = __float_as_uint(f);
  return (u + 0x7fffu + ((u >> 16) & 1u)) >> 16;
}
__device__ __forceinline__ float bf_f(unsigned h) { return __uint_as_float(h << 16); }

// split 8 f32 into hi/lo bf16 fragments (K-order = array order)
__device__ __forceinline__ void split8(const float* e, bhalf8& hi, bhalf8& lo) {
  union { int i[4]; bhalf8 v; } H, L;
#pragma unroll
  for (int w = 0; w < 4; ++w) {
    unsigned h0 = bf_rne(e[2 * w]), h1 = bf_rne(e[2 * w + 1]);
    unsigned l0 = bf_rne(e[2 * w] - bf_f(h0));
    unsigned l1 = bf_rne(e[2 * w + 1] - bf_f(h1));
    H.i[w] = (int)(h0 | (h1 << 16));
    L.i[w] = (int)(l0 | (l1 << 16));
  }
  hi = H.v; lo = L.v;
}

// ---------------- weight absmean: partial sums ----------------
__global__ __launch_bounds__(256) void wabs_kernel(
    const float* __restrict__ Wq, const float* __restrict__ Wk,
    const float* __restrict__ Wv, const float* __restrict__ Wo,
    float* __restrict__ part) {
  const int widx = blockIdx.y;
  const float* W = widx == 0 ? Wq : widx == 1 ? Wk : widx == 2 ? Wv : Wo;
  const float4* W4 = (const float4*)W;
  const int tid = threadIdx.x;
  size_t base = (size_t)blockIdx.x * 256 + tid;
  float s = 0.f;
#pragma unroll
  for (int i = 0; i < 4; ++i) {
    float4 w = W4[base + (size_t)i * 65536];
    s += fabsf(w.x) + fabsf(w.y) + fabsf(w.z) + fabsf(w.w);
  }
  s = wave_sum(s);
  __shared__ float red[4];
  if ((tid & 63) == 0) red[tid >> 6] = s;
  __syncthreads();
  if (tid == 0) part[widx * 256 + blockIdx.x] = red[0] + red[1] + red[2] + red[3];
}

__global__ __launch_bounds__(256) void wmean_kernel(
    const float* __restrict__ part, float* __restrict__ wmean) {
  const int b = blockIdx.x;
  float v = part[b * 256 + threadIdx.x];
  v = wave_sum(v);
  __shared__ float red[4];
  if ((threadIdx.x & 63) == 0) red[threadIdx.x >> 6] = v;
  __syncthreads();
  if (threadIdx.x == 0)
    wmean[b] = fmaxf((red[0] + red[1] + red[2] + red[3]) * (1.0f / 1048576.0f), 1e-5f);
}

// ---------------- ternary weight quant ----------------
__global__ __launch_bounds__(256) void wquant_kernel(
    const float* __restrict__ Wq, const float* __restrict__ Wk,
    const float* __restrict__ Wv, const float* __restrict__ Wo,
    signed char* __restrict__ out, const float* __restrict__ wmean) {
  const int widx = blockIdx.y;
  const float* W = widx == 0 ? Wq : widx == 1 ? Wk : widx == 2 ? Wv : Wo;
  const float scale = 1.0f / wmean[widx];
  size_t i4 = (size_t)blockIdx.x * 256 + threadIdx.x;
  float4 w = ((const float4*)W)[i4];
  char4 q;
  q.x = (signed char)fminf(fmaxf(rintf(w.x * scale), -1.f), 1.f);
  q.y = (signed char)fminf(fmaxf(rintf(w.y * scale), -1.f), 1.f);
  q.z = (signed char)fminf(fmaxf(rintf(w.z * scale), -1.f), 1.f);
  q.w = (signed char)fminf(fmaxf(rintf(w.w * scale), -1.f), 1.f);
  ((char4*)(out + (size_t)widx * NWEL))[i4] = q;
}

// ---------------- per-token activation quant ----------------
__global__ __launch_bounds__(256) void actquant_kernel(
    const float* __restrict__ in0, const float* __restrict__ in1, const float* __restrict__ in2,
    signed char* __restrict__ o0, signed char* __restrict__ o1, signed char* __restrict__ o2,
    float* __restrict__ r0, float* __restrict__ r1, float* __restrict__ r2) {
  const int which = blockIdx.y;
  const float* x = which == 0 ? in0 : which == 1 ? in1 : in2;
  signed char* xq = which == 0 ? o0 : which == 1 ? o1 : o2;
  float* rs = which == 0 ? r0 : which == 1 ? r1 : r2;
  const int row = blockIdx.x, tid = threadIdx.x;
  float4 v = ((const float4*)(x + (size_t)row * NE))[tid];
  float am = fmaxf(fmaxf(fabsf(v.x), fabsf(v.y)), fmaxf(fabsf(v.z), fabsf(v.w)));
  am = wave_max(am);
  __shared__ float red[4];
  if ((tid & 63) == 0) red[tid >> 6] = am;
  __syncthreads();
  am = fmaxf(fmaxf(red[0], red[1]), fmaxf(red[2], red[3]));
  float cm = fmaxf(am, 1e-5f);
  float scale = 127.0f / cm;
  char4 q;
  q.x = (signed char)fminf(fmaxf(rintf(v.x * scale), -128.f), 127.f);
  q.y = (signed char)fminf(fmaxf(rintf(v.y * scale), -128.f), 127.f);
  q.z = (signed char)fminf(fmaxf(rintf(v.z * scale), -128.f), 127.f);
  q.w = (signed char)fminf(fmaxf(rintf(v.w * scale), -128.f), 127.f);
  ((char4*)(xq + (size_t)row * NE))[tid] = q;
  if (tid == 0) rs[row] = cm * (1.0f / 127.0f);
}

// ---------------- int8 GEMM ----------------
__global__ __launch_bounds__(256) void gemm_kernel(
    const signed char* __restrict__ A, const signed char* __restrict__ B,
    const float* __restrict__ rowscale, const float* __restrict__ wmeanp,
    const float* __restrict__ bias, float* __restrict__ C) {
  __shared__ signed char As[128 * 64];
  __shared__ signed char Bs[128 * 64];
  const int tid = threadIdx.x;
  const int lane = tid & 63, wid = tid >> 6;
  const int wr = wid >> 1, wc = wid & 1;
  const int bm = blockIdx.y, bn = blockIdx.x;
  const signed char* Ab = A + (size_t)bm * 128 * 1024;
  const signed char* Bb = B + (size_t)bn * 128 * 1024;

  v4i acc[4][4];
#pragma unroll
  for (int i = 0; i < 4; ++i)
#pragma unroll
    for (int j = 0; j < 4; ++j) acc[i][j] = (v4i){0, 0, 0, 0};

  const int o0 = wid * 2048 + lane * 16;
  const int r0 = o0 >> 6, c0 = o0 & 63;
  const int o1 = o0 + 1024;
  const int r1 = o1 >> 6, c1 = o1 & 63;
  const int klo = (lane >> 4) << 4;
  const int arow0 = (wr * 64 + (lane & 15)) * 64 + klo;
  const int brow0 = (wc * 64 + (lane & 15)) * 64 + klo;

  for (int k0 = 0; k0 < 1024; k0 += 64) {
    gload_lds16(Ab + (size_t)r0 * 1024 + k0 + c0, &As[wid * 2048]);
    gload_lds16(Ab + (size_t)r1 * 1024 + k0 + c1, &As[wid * 2048 + 1024]);
    gload_lds16(Bb + (size_t)r0 * 1024 + k0 + c0, &Bs[wid * 2048]);
    gload_lds16(Bb + (size_t)r1 * 1024 + k0 + c1, &Bs[wid * 2048 + 1024]);
    __syncthreads();
    v4i af[4], bf[4];
#pragma unroll
    for (int i = 0; i < 4; ++i) af[i] = *(const v4i*)&As[arow0 + i * 16 * 64];
#pragma unroll
    for (int j = 0; j < 4; ++j) bf[j] = *(const v4i*)&Bs[brow0 + j * 16 * 64];
#pragma unroll
    for (int i = 0; i < 4; ++i)
#pragma unroll
      for (int j = 0; j < 4; ++j)
        acc[i][j] = __builtin_amdgcn_mfma_i32_16x16x64_i8(af[i], bf[j], acc[i][j], 0, 0, 0);
    __syncthreads();
  }

  const float wmean = *wmeanp;
  const int row0 = bm * 128 + wr * 64 + ((lane >> 4) << 2);
  const int col0 = bn * 128 + wc * 64 + (lane & 15);
#pragma unroll
  for (int i = 0; i < 4; ++i) {
#pragma unroll
    for (int r = 0; r < 4; ++r) {
      const int m = row0 + i * 16 + r;
      const float rsw = rowscale[m] * wmean;
#pragma unroll
      for (int j = 0; j < 4; ++j) {
        const int n = col0 + j * 16;
        C[(size_t)m * 1024 + n] = (float)acc[i][j][r] * rsw + bias[n];
      }
    }
  }
}

// ---------------- fused attention + layernorm + actquant ----------------
// One WAVE per token (4 waves/block, no __syncthreads). MFMA bf16 hi/lo split
// => f32-grade accuracy. q,k,v fragment loads direct from global (no staging).
// Only LDS: 1.25KB/wave scratch for the 16x16 p transpose (padded stride 20).
__global__ __launch_bounds__(256) void attn_kernel(
    const float* __restrict__ qf, const float* __restrict__ kf,
    const float* __restrict__ vf, const float* __restrict__ gamma,
    const float* __restrict__ beta, signed char* __restrict__ xq,
    float* __restrict__ rs) {
  __shared__ unsigned p32s[4][16 * 20];
  const int tid = threadIdx.x;
  const int lane = tid & 63, wid = tid >> 6;
  const int token = blockIdx.x * 4 + wid;
  const float* qrow = qf + (size_t)token * 1024;
  const float* krow = kf + (size_t)token * 1024;
  const float* vrow = vf + (size_t)token * 1024;

  const int fr = lane & 15;   // frag row/col (h for A, g for B, dd for PV-D)
  const int fg = lane >> 4;   // lane group 0..3
  const int g0 = (fg & 1) * 8;

  // ---- issue all global loads up front ----
  // q/k: A/B frag source = row fr, d = fg*8 (+32 for half 1), 8 consecutive f32
  float qe0[8], qe1[8], ke0[8], ke1[8];
  {
    float4 a0 = *(const float4*)(qrow + fr * 64 + fg * 8);
    float4 a1 = *(const float4*)(qrow + fr * 64 + fg * 8 + 4);
    float4 a2 = *(const float4*)(qrow + fr * 64 + 32 + fg * 8);
    float4 a3 = *(const float4*)(qrow + fr * 64 + 32 + fg * 8 + 4);
    qe0[0]=a0.x; qe0[1]=a0.y; qe0[2]=a0.z; qe0[3]=a0.w;
    qe0[4]=a1.x; qe0[5]=a1.y; qe0[6]=a1.z; qe0[7]=a1.w;
    qe1[0]=a2.x; qe1[1]=a2.y; qe1[2]=a2.z; qe1[3]=a2.w;
    qe1[4]=a3.x; qe1[5]=a3.y; qe1[6]=a3.z; qe1[7]=a3.w;
    float4 b0 = *(const float4*)(krow + fr * 64 + fg * 8);
    float4 b1 = *(const float4*)(krow + fr * 64 + fg * 8 + 4);
    float4 b2 = *(const float4*)(krow + fr * 64 + 32 + fg * 8);
    float4 b3 = *(const float4*)(krow + fr * 64 + 32 + fg * 8 + 4);
    ke0[0]=b0.x; ke0[1]=b0.y; ke0[2]=b0.z; ke0[3]=b0.w;
    ke0[4]=b1.x; ke0[5]=b1.y; ke0[6]=b1.z; ke0[7]=b1.w;
    ke1[0]=b2.x; ke1[1]=b2.y; ke1[2]=b2.z; ke1[3]=b2.w;
    ke1[4]=b3.x; ke1[5]=b3.y; ke1[6]=b3.z; ke1[7]=b3.w;
  }
  // v for PV B-frags: v[g0+i][16j+fr], i=0..7, j=0..3 (column runs, stride 64)
  float val[4][8];
#pragma unroll
  for (int j = 0; j < 4; ++j)
#pragma unroll
    for (int i = 0; i < 8; ++i)
      val[j][i] = vrow[(g0 + i) * 64 + 16 * j + fr];

  // ---- scores: sim = q·k^T / 8 via 6 MFMAs (hi/lo split) ----
  bhalf8 qh0, ql0, qh1, ql1, kh0, kl0, kh1, kl1;
  split8(qe0, qh0, ql0); split8(qe1, qh1, ql1);
  split8(ke0, kh0, kl0); split8(ke1, kh1, kl1);
  f32x4 sacc = {0.f, 0.f, 0.f, 0.f};
  sacc = __builtin_amdgcn_mfma_f32_16x16x32_bf16(qh0, kh0, sacc, 0, 0, 0);
  sacc = __builtin_amdgcn_mfma_f32_16x16x32_bf16(qh0, kl0, sacc, 0, 0, 0);
  sacc = __builtin_amdgcn_mfma_f32_16x16x32_bf16(ql0, kh0, sacc, 0, 0, 0);
  sacc = __builtin_amdgcn_mfma_f32_16x16x32_bf16(qh1, kh1, sacc, 0, 0, 0);
  sacc = __builtin_amdgcn_mfma_f32_16x16x32_bf16(qh1, kl1, sacc, 0, 0, 0);
  sacc = __builtin_amdgcn_mfma_f32_16x16x32_bf16(ql1, kh1, sacc, 0, 0, 0);

  // D layout: lane holds sim[h = fg*4 + r][g = fr], r=0..3.
  // ---- softmax over g: reduce across the 16-lane group ----
  float p[4];
#pragma unroll
  for (int r = 0; r < 4; ++r) {
    float s = sacc[r] * 0.125f;
    float mx = s;
#pragma unroll
    for (int o = 8; o; o >>= 1) mx = fmaxf(mx, __shfl_xor(mx, o, 16));
    float e = __expf(s - mx);
    float sum = e;
#pragma unroll
    for (int o = 8; o; o >>= 1) sum += __shfl_xor(sum, o, 16);
    p[r] = e / sum;
  }

  // ---- p transpose via LDS scratch (hi|lo packed u32, stride 20) ----
  unsigned* ps = p32s[wid];
#pragma unroll
  for (int r = 0; r < 4; ++r) {
    unsigned h16 = bf_rne(p[r]);
    unsigned l16 = bf_rne(p[r] - bf_f(h16));
    ps[(fg * 4 + r) * 20 + fr] = h16 | (l16 << 16);
  }
  // same-wave DS ops are in-order; read back A-frag rows
  int4 pa = *(const int4*)&ps[fr * 20 + g0];
  int4 pb = *(const int4*)&ps[fr * 20 + g0 + 4];
  // A1 = [ph | pl] (k<16 -> hi, k>=16 -> lo); A2 = [ph | 0]
  bhalf8 A1, A2;
  {
    const unsigned sh = (fg >= 2) ? 16u : 0u;
    union { int i[4]; bhalf8 v; } U, Z;
    U.i[0] = (int)(((pa.x >> sh) & 0xffffu) | (((pa.y >> sh) & 0xffffu) << 16));
    U.i[1] = (int)(((pa.z >> sh) & 0xffffu) | (((pa.w >> sh) & 0xffffu) << 16));
    U.i[2] = (int)(((pb.x >> sh) & 0xffffu) | (((pb.y >> sh) & 0xffffu) << 16));
    U.i[3] = (int)(((pb.z >> sh) & 0xffffu) | (((pb.w >> sh) & 0xffffu) << 16));
    A1 = U.v;
    Z.i[0] = (fg >= 2) ? 0 : U.i[0];
    Z.i[1] = (fg >= 2) ? 0 : U.i[1];
    Z.i[2] = (fg >= 2) ? 0 : U.i[2];
    Z.i[3] = (fg >= 2) ? 0 : U.i[3];
    A2 = Z.v;
  }

  // ---- PV: x = p·v via 2 MFMAs per 16-d chunk ----
  // A1·[vh;vh] = (ph+pl)·vh ; A2·[vl;vl] = ph·vl
  f32x4 pacc[4];
#pragma unroll
  for (int j = 0; j < 4; ++j) {
    bhalf8 Bh, Bl;
    split8(val[j], Bh, Bl);
    f32x4 a = {0.f, 0.f, 0.f, 0.f};
    a = __builtin_amdgcn_mfma_f32_16x16x32_bf16(A1, Bh, a, 0, 0, 0);
    a = __builtin_amdgcn_mfma_f32_16x16x32_bf16(A2, Bl, a, 0, 0, 0);
    pacc[j] = a;
  }
  // pacc[j][r] = x[h = fg*4 + r][16j + fr]

  // ---- LayerNorm stats over all 1024 ----
  float s = 0.f, sq = 0.f;
#pragma unroll
  for (int j = 0; j < 4; ++j)
#pragma unroll
    for (int r = 0; r < 4; ++r) {
      float x = pacc[j][r];
      s += x; sq += x * x;
    }
  s = wave_sum(s); sq = wave_sum(sq);
  const float mu = s * (1.0f / 1024.0f);
  const float var = sq * (1.0f / 1024.0f) - mu * mu;
  const float rstd = rsqrtf(var + 1e-5f);

  // ---- gamma/beta, absmax quant ----
  float y[16];
  float am = 0.f;
#pragma unroll
  for (int j = 0; j < 4; ++j)
#pragma unroll
    for (int r = 0; r < 4; ++r) {
      const int idx = (fg * 4 + r) * 64 + 16 * j + fr;
      float yy = (pacc[j][r] - mu) * rstd * gamma[idx] + beta[idx];
      y[j * 4 + r] = yy;
      am = fmaxf(am, fabsf(yy));
    }
  am = wave_max(am);
  const float cm = fmaxf(am, 1e-5f);
  const float scale = 127.0f / cm;
  signed char* orow = xq + (size_t)token * 1024;
#pragma unroll
  for (int j = 0; j < 4; ++j)
#pragma unroll
    for (int r = 0; r < 4; ++r) {
      const int idx = (fg * 4 + r) * 64 + 16 * j + fr;
      orow[idx] = (signed char)fminf(fmaxf(rintf(y[j * 4 + r] * scale), -128.f), 127.f);
    }
  if (lane == 0) rs[token] = cm * (1.0f / 127.0f);
}

extern "C" void kernel_launch(void* const* d_in, const int* in_sizes, int n_in,
                              void* d_out, int out_size, void* d_ws, size_t ws_size,
                              hipStream_t stream) {
  const float* query = (const float*)d_in[0];
  const float* key   = (const float*)d_in[1];
  const float* value = (const float*)d_in[2];
  const float* Wq = (const float*)d_in[3];
  const float* bq = (const float*)d_in[4];
  const float* Wk = (const float*)d_in[5];
  const float* bk = (const float*)d_in[6];
  const float* Wv = (const float*)d_in[7];
  const float* bv = (const float*)d_in[8];
  const float* gamma = (const float*)d_in[9];
  const float* beta  = (const float*)d_in[10];
  const float* Wo = (const float*)d_in[11];
  const float* bo = (const float*)d_in[12];

  uint8_t* ws = (uint8_t*)d_ws;
  signed char* wqt = (signed char*)ws;                        // 4 MB: 4x ternary weights
  float* wpart = (float*)(ws + ((size_t)4 << 20));            // 4x256 partials
  float* wmean = (float*)(ws + ((size_t)4 << 20) + 16384);    // 4 means
  float* rs_q = (float*)(ws + ((size_t)5 << 20));             // 4x 128KB rowscales
  float* rs_k = rs_q + NTOK;
  float* rs_v = rs_k + NTOK;
  float* rs_a = rs_v + NTOK;
  signed char* xq_q = (signed char*)(ws + ((size_t)8 << 20)); // 3x 32MB int8 activations
  signed char* xq_k = xq_q + ((size_t)32 << 20);
  signed char* xq_v = xq_k + ((size_t)32 << 20);
  signed char* xq_a = xq_q;                                   // reuse (q consumed)
  float* qf = (float*)(ws + ((size_t)104 << 20));             // 128 MB
  float* kf = (float*)(ws + ((size_t)232 << 20));             // 128 MB
  float* vf = (float*)d_out;                                  // reuse d_out as v buffer
  float* out = (float*)d_out;

  wabs_kernel<<<dim3(256, 4), 256, 0, stream>>>(Wq, Wk, Wv, Wo, wpart);
  wmean_kernel<<<4, 256, 0, stream>>>(wpart, wmean);
  wquant_kernel<<<dim3(1024, 4), 256, 0, stream>>>(Wq, Wk, Wv, Wo, wqt, wmean);
  actquant_kernel<<<dim3(NTOK, 3), 256, 0, stream>>>(query, key, value,
                                                     xq_q, xq_k, xq_v, rs_q, rs_k, rs_v);
  gemm_kernel<<<dim3(8, 256), 256, 0, stream>>>(xq_q, wqt + 0 * (size_t)NWEL, rs_q, wmean + 0, bq, qf);
  gemm_kernel<<<dim3(8, 256), 256, 0, stream>>>(xq_k, wqt + 1 * (size_t)NWEL, rs_k, wmean + 1, bk, kf);
  gemm_kernel<<<dim3(8, 256), 256, 0, stream>>>(xq_v, wqt + 2 * (size_t)NWEL, rs_v, wmean + 2, bv, vf);
  attn_kernel<<<NTOK / 4, 256, 0, stream>>>(qf, kf, vf, gamma, beta, xq_a, rs_a);
  gemm_kernel<<<dim3(8, 256), 256, 0, stream>>>(xq_a, wqt + 3 * (size_t)NWEL, rs_a, wmean + 3, bo, out);
}